// Round 11
// baseline (124.204 us; speedup 1.0000x reference)
//
#include <hip/hip_runtime.h>
#include <hip/hip_bf16.h>

// HD^-0.5 * log2(e): scores scaled so softmax uses exp2 directly.
#define QSC (0.17677669529663687f * 1.4426950408889634f)

typedef __attribute__((ext_vector_type(8))) short bf16x8;
typedef __attribute__((ext_vector_type(4))) float f32x4;
typedef unsigned short u16;

union FragU { unsigned u[4]; uint4 q; bf16x8 v; };

__device__ inline u16 f2bu(float a) {
  union { __hip_bfloat16 h; u16 s; } c;
  c.h = __float2bfloat16(a);
  return c.s;
}
// Single-instruction packed f32->bf16 (RNE): lo -> low 16, hi -> high 16.
__device__ inline unsigned pk2(float lo, float hi) {
  unsigned r;
  asm("v_cvt_pk_bf16_f32 %0, %1, %2" : "=v"(r) : "v"(lo), "v"(hi));
  return r;
}
// Raw v_exp_f32 (2^x). Scores are O(1): no subnormal fixup needed.
__device__ inline float exp2r(float x) {
  float r;
  asm("v_exp_f32 %0, %1" : "=v"(r) : "v"(x));
  return r;
}
// Async global->LDS, 16B per lane. LDS dest is wave-uniform base + lane*16.
__device__ inline void gl16(const u16* g, u16* l) {
  __builtin_amdgcn_global_load_lds(
      (const __attribute__((address_space(1))) unsigned int*)g,
      (__attribute__((address_space(3))) unsigned int*)l, 16, 0, 0);
}
__device__ inline void waitvm0() {
  asm volatile("s_waitcnt vmcnt(0)" ::: "memory");
}

// ---------------------------------------------------------------------------
// x transpose+convert: xbT[b][n(4096)][c(256)] bf16 from x[b][c][n] f32.
// grid (64 nchunk, 8 cchunk, 9), block 256.  z==8 plane does weight prep
// (bf16 conversion; ws k-reordered to [co][tap*256+ci]) and zeroes xr
// (required every iteration: harness re-poisons the workspace, and the sr
// split-K now accumulates into xr via atomicAdd).
// ---------------------------------------------------------------------------
__global__ __launch_bounds__(256) void k_xT(
    const float* __restrict__ X, u16* __restrict__ XT,
    const float* __restrict__ wq, const float* __restrict__ wproj,
    const float* __restrict__ ws,
    const float* __restrict__ w0, const float* __restrict__ w1,
    const float* __restrict__ w2, const float* __restrict__ w3,
    u16* __restrict__ wqb, u16* __restrict__ wpb,
    u16* __restrict__ wsb, u16* __restrict__ wkvb,
    float* __restrict__ xr) {
  if (blockIdx.z == 8) {
    int which = blockIdx.y;
    int tid = blockIdx.x * 256 + threadIdx.x;  // 0..16383
    const int ST = 16384;
    if (which == 0) {
      for (int i = tid; i < 131072; i += ST) wqb[i] = f2bu(wq[i]);
    } else if (which == 1) {
      for (int i = tid; i < 131072; i += ST) wpb[i] = f2bu(wproj[i]);
    } else if (which == 2) {
      for (int i = tid; i < 1048576; i += ST) {
        int co = i >> 12, rem = i & 4095, tap = rem >> 8, ci = rem & 255;
        wsb[i] = f2bu(ws[co * 4096 + ci * 16 + tap]);
      }
    } else if (which < 7) {
      const float* src = (which == 3) ? w0 : (which == 4) ? w1 : (which == 5) ? w2 : w3;
      u16* dst = wkvb + (size_t)(which - 3) * 65536;
      for (int i = tid; i < 65536; i += ST) dst[i] = f2bu(src[i]);
    } else {
      // zero xr (524288 f32 = 131072 float4)
      float4* xz = (float4*)xr;
      float4 z4 = make_float4(0.f, 0.f, 0.f, 0.f);
      for (int i = tid; i < 131072; i += ST) xz[i] = z4;
    }
    return;
  }
  __shared__ float L[32 * 65];
  int n0 = blockIdx.x * 64, c0 = blockIdx.y * 32, b = blockIdx.z;
  int t = threadIdx.x;
#pragma unroll
  for (int i = 0; i < 8; ++i) {
    int idx = i * 256 + t;
    int r = idx >> 6, nn = idx & 63;
    L[r * 65 + nn] = X[((size_t)(b * 256 + c0 + r)) * 4096 + n0 + nn];
  }
  __syncthreads();
  int nn = t >> 2, cq = t & 3;
  uint4 u;
  u.x = pk2(L[(cq * 8 + 0) * 65 + nn], L[(cq * 8 + 1) * 65 + nn]);
  u.y = pk2(L[(cq * 8 + 2) * 65 + nn], L[(cq * 8 + 3) * 65 + nn]);
  u.z = pk2(L[(cq * 8 + 4) * 65 + nn], L[(cq * 8 + 5) * 65 + nn]);
  u.w = pk2(L[(cq * 8 + 6) * 65 + nn], L[(cq * 8 + 7) * 65 + nn]);
  *(uint4*)(XT + ((size_t)b * 4096 + n0 + nn) * 256 + c0 + cq * 8) = u;
}

// ---------------------------------------------------------------------------
// FUSED qproj + sr GEMM (R8 2-phase staging).  blockIdx.x < 32: qproj tile;
// else sr K-split ks = blockIdx.x-32, accumulating partials directly into
// xr via atomicAdd (psr round-trip eliminated; xr zeroed by k_xT).
// grid (40, 4, 8), block 256.
// ---------------------------------------------------------------------------
__global__ __launch_bounds__(256) void k_gemm_x(
    const u16* __restrict__ XT, const u16* __restrict__ Wqb,
    const float* __restrict__ bias, u16* __restrict__ Qb,
    const u16* __restrict__ Wsb, float* __restrict__ xr) {
  __shared__ __align__(16) u16 SM[16384];  // As[2][4096] | Bs[2][4096]
  int b = blockIdx.z;
  int t = threadIdx.x, w = t >> 6, l = t & 63, g = l >> 4, lq = l & 15;
  int wr = w >> 1, wc = w & 1;
  const u16* Xb = XT + (size_t)b * 4096 * 256;
  int srow = w * 32 + (l >> 2), scol = (l & 3) * 8;
  u16* lA = SM + w * 1024;         // wave-uniform staging bases
  u16* lB = SM + 8192 + w * 1024;

  f32x4 acc[4][4];
#pragma unroll
  for (int ms = 0; ms < 4; ++ms)
#pragma unroll
    for (int ns = 0; ns < 4; ++ns) acc[ms][ns] = {0.f, 0.f, 0.f, 0.f};

  if (blockIdx.x < 32) {
    // ================= qproj path =================
    int n0 = blockIdx.x * 128, m0 = blockIdx.y * 128;
    const u16* gA = Wqb + (size_t)(m0 + srow) * 256 + scol;
    const u16* gB = Xb + (size_t)(n0 + srow) * 256 + scol;

    gl16(gA, lA); gl16(gA + 16 * 256, lA + 512);
    gl16(gB, lB); gl16(gB + 16 * 256, lB + 512);
    waitvm0();
    __syncthreads();
#pragma unroll
    for (int kt = 0; kt < 8; ++kt) {
      int cur = kt & 1;
      if (kt < 7) {
        int sel = cur ^ 1, ko = (kt + 1) * 32;
        gl16(gA + ko, lA + sel * 4096); gl16(gA + 16 * 256 + ko, lA + sel * 4096 + 512);
        gl16(gB + ko, lB + sel * 4096); gl16(gB + 16 * 256 + ko, lB + sel * 4096 + 512);
      }
      const u16* Ab = SM + cur * 4096;
      const u16* Bb = SM + 8192 + cur * 4096;
      FragU a[4], bb[4];
#pragma unroll
      for (int ms = 0; ms < 4; ++ms)
        a[ms].q = *(const uint4*)(Ab + (wr * 64 + ms * 16 + lq) * 32 + g * 8);
#pragma unroll
      for (int ns = 0; ns < 4; ++ns)
        bb[ns].q = *(const uint4*)(Bb + (wc * 64 + ns * 16 + lq) * 32 + g * 8);
#pragma unroll
      for (int ms = 0; ms < 4; ++ms)
#pragma unroll
        for (int ns = 0; ns < 4; ++ns)
          acc[ms][ns] = __builtin_amdgcn_mfma_f32_16x16x32_bf16(a[ms].v, bb[ns].v, acc[ms][ns], 0, 0, 0);
      waitvm0();
      __syncthreads();
    }

    float bR[4][4];
#pragma unroll
    for (int ms = 0; ms < 4; ++ms)
#pragma unroll
      for (int r = 0; r < 4; ++r) bR[ms][r] = bias[m0 + wr * 64 + ms * 16 + g * 4 + r];

    // epilogue: acc -> LDS [n_local(128)][m_local(128)] u16 (XOR-swizzled),
    // then coalesced 16B stores to qb attn layout.
    char* Lc = (char*)SM;
#pragma unroll
    for (int ms = 0; ms < 4; ++ms)
#pragma unroll
      for (int ns = 0; ns < 4; ++ns) {
        int nl = wc * 64 + ns * 16 + lq;
        int mb2 = (wr * 64 + ms * 16 + g * 4) * 2;
        int off = (nl * 256 + mb2) ^ ((nl & 7) << 4);
        *(uint2*)(Lc + off) = make_uint2(
            pk2((acc[ms][ns][0] + bR[ms][0]) * QSC, (acc[ms][ns][1] + bR[ms][1]) * QSC),
            pk2((acc[ms][ns][2] + bR[ms][2]) * QSC, (acc[ms][ns][3] + bR[ms][3]) * QSC));
      }
    __syncthreads();
    int sh0 = m0 >> 5;
#pragma unroll
    for (int rr = 0; rr < 8; ++rr) {
      int idx = rr * 256 + t;
      int ch = idx & 3, shl = (idx >> 2) & 3, nn = idx >> 4;
      int off = (nn * 256 + shl * 64 + ch * 16) ^ ((nn & 7) << 4);
      uint4 v = *(const uint4*)(Lc + off);
      *(uint4*)(Qb + ((size_t)(b * 16 + sh0 + shl) * 4096 + n0 + nn) * 32 + ch * 8) = v;
    }
  } else {
    // ================= sr path (K-split by 8, atomic accumulate) ==========
    int ks = blockIdx.x - 32;
    int m0 = (blockIdx.y >> 1) * 128, n0 = (blockIdx.y & 1) * 128;
    const u16* gA = Wsb + (size_t)(m0 + srow) * 4096 + scol;
    int nA = n0 + srow, nB = nA + 16;
    int iA = nA >> 4, jA = nA & 15, iB = nB >> 4, jB = nB & 15;

#define SR_STAGE(sel, kt) {                                                   \
    int ktg = ks * 16 + (kt);                                                 \
    int tap = ktg >> 3, ci0 = (ktg & 7) * 32;                                 \
    int ky = tap >> 2, kx = tap & 3;                                          \
    gl16(gA + ktg * 32, lA + (sel) * 4096);                                   \
    gl16(gA + (size_t)16 * 4096 + ktg * 32, lA + (sel) * 4096 + 512);         \
    int pixA = (4 * iA + ky) * 64 + 4 * jA + kx;                              \
    int pixB = (4 * iB + ky) * 64 + 4 * jB + kx;                              \
    gl16(Xb + (size_t)pixA * 256 + ci0 + scol, lB + (sel) * 4096);            \
    gl16(Xb + (size_t)pixB * 256 + ci0 + scol, lB + (sel) * 4096 + 512); }

    SR_STAGE(0, 0);
    waitvm0();
    __syncthreads();
#pragma unroll
    for (int kt = 0; kt < 16; ++kt) {
      int cur = kt & 1;
      if (kt < 15) SR_STAGE(cur ^ 1, kt + 1);
      const u16* Ab = SM + cur * 4096;
      const u16* Bb = SM + 8192 + cur * 4096;
      FragU a[4], bb[4];
#pragma unroll
      for (int ms = 0; ms < 4; ++ms)
        a[ms].q = *(const uint4*)(Ab + (wr * 64 + ms * 16 + lq) * 32 + g * 8);
#pragma unroll
      for (int ns = 0; ns < 4; ++ns)
        bb[ns].q = *(const uint4*)(Bb + (wc * 64 + ns * 16 + lq) * 32 + g * 8);
#pragma unroll
      for (int ms = 0; ms < 4; ++ms)
#pragma unroll
        for (int ns = 0; ns < 4; ++ns)
          acc[ms][ns] = __builtin_amdgcn_mfma_f32_16x16x32_bf16(a[ms].v, bb[ns].v, acc[ms][ns], 0, 0, 0);
      waitvm0();
      __syncthreads();
    }
#undef SR_STAGE
#pragma unroll
    for (int ms = 0; ms < 4; ++ms)
#pragma unroll
      for (int ns = 0; ns < 4; ++ns) {
        int n = n0 + wc * 64 + ns * 16 + lq;
#pragma unroll
        for (int r = 0; r < 4; ++r) {
          int m = m0 + wr * 64 + ms * 16 + g * 4 + r;
          atomicAdd(xr + ((size_t)(b * 256) + m) * 256 + n, acc[ms][ns][r]);
        }
      }
  }
}

// ---------------------------------------------------------------------------
// Fused: load xr (+bias) -> LDS; emit xrT bf16 [b][pix][c] AND depthwise
// 3x3 -> tkT/tvT bf16 [b][pix][c].  (psr reduce gone: xr is final via
// atomics.)  grid (16 cg, 8 b), block 256 = pixels.
// ---------------------------------------------------------------------------
__global__ __launch_bounds__(256) void k_srdw(
    const float* __restrict__ xr, const float* __restrict__ bias,
    const float* __restrict__ wkd, const float* __restrict__ bkd,
    const float* __restrict__ wvd, const float* __restrict__ bvd,
    u16* __restrict__ xrT, u16* __restrict__ TKt, u16* __restrict__ TVt) {
  __shared__ float L[16 * 256];
  int cg = blockIdx.x, b = blockIdx.y, t = threadIdx.x;
#pragma unroll
  for (int r = 0; r < 16; ++r) {
    int c = cg * 16 + r;
    L[r * 256 + t] = xr[((size_t)(b * 256 + c)) * 256 + t] + bias[c];
  }
  __syncthreads();
  {
    unsigned wv[8];
#pragma unroll
    for (int r2 = 0; r2 < 8; ++r2)
      wv[r2] = pk2(L[(2 * r2) * 256 + t], L[(2 * r2 + 1) * 256 + t]);
    u16* dst = xrT + ((size_t)b * 256 + t) * 256 + cg * 16;
    *(uint4*)(dst + 0) = make_uint4(wv[0], wv[1], wv[2], wv[3]);
    *(uint4*)(dst + 8) = make_uint4(wv[4], wv[5], wv[6], wv[7]);
  }
  int i = t >> 4, j = t & 15;
  unsigned wk[8], wvv[8];
#pragma unroll
  for (int r2 = 0; r2 < 8; ++r2) {
    int c0 = cg * 16 + 2 * r2;
    float ak0 = bkd[c0], ak1 = bkd[c0 + 1];
    float av0 = bvd[c0], av1 = bvd[c0 + 1];
#pragma unroll
    for (int ky = 0; ky < 3; ++ky) {
      int ii = i + ky - 1;
      if (ii < 0 || ii > 15) continue;
#pragma unroll
      for (int kx = 0; kx < 3; ++kx) {
        int jj = j + kx - 1;
        if (jj < 0 || jj > 15) continue;
        float v0 = L[(2 * r2) * 256 + ii * 16 + jj];
        float v1 = L[(2 * r2 + 1) * 256 + ii * 16 + jj];
        float wk0 = wkd[c0 * 9 + ky * 3 + kx], wk1 = wkd[(c0 + 1) * 9 + ky * 3 + kx];
        float wv0 = wvd[c0 * 9 + ky * 3 + kx], wv1 = wvd[(c0 + 1) * 9 + ky * 3 + kx];
        ak0 = fmaf(v0, wk0, ak0); ak1 = fmaf(v1, wk1, ak1);
        av0 = fmaf(v0, wv0, av0); av1 = fmaf(v1, wv1, av1);
      }
    }
    wk[r2] = pk2(ak0, ak1);
    wvv[r2] = pk2(av0, av1);
  }
  u16* dk = TKt + ((size_t)b * 256 + t) * 256 + cg * 16;
  u16* dv = TVt + ((size_t)b * 256 + t) * 256 + cg * 16;
  *(uint4*)(dk + 0) = make_uint4(wk[0], wk[1], wk[2], wk[3]);
  *(uint4*)(dk + 8) = make_uint4(wk[4], wk[5], wk[6], wk[7]);
  *(uint4*)(dv + 0) = make_uint4(wvv[0], wvv[1], wvv[2], wvv[3]);
  *(uint4*)(dv + 8) = make_uint4(wvv[4], wvv[5], wvv[6], wvv[7]);
}

// ---------------------------------------------------------------------------
// K/V pointwise projections as MFMA GEMM -> bf16 pre-swizzled 16KB LDS
// images, one per (which, b, h):  KV[(which*64 + b*8 + h)*8192 u16].
//   K image byte: ((n*64 + (d>>3)*16) ^ (((n>>1)&7)<<4)) + (d&7)*2
//   V image byte:  (d*512 + n*2)      ^ (((d>>1)&7)<<4)
// grid (4 which, 8 m, 8 b) = 256 blocks (1/CU).
// ---------------------------------------------------------------------------
__global__ __launch_bounds__(256) void k_gemm_kv(
    const u16* __restrict__ xrT, const u16* __restrict__ tkT, const u16* __restrict__ tvT,
    const u16* __restrict__ wkvb,
    const float* __restrict__ bak_p, const float* __restrict__ bav_p,
    const float* __restrict__ bek, const float* __restrict__ bev,
    u16* __restrict__ KV) {
  int which = blockIdx.x, m0 = blockIdx.y * 32, b = blockIdx.z;
  const u16* XT; const float* bias;
  if (which == 0)      { XT = tkT; bias = bak_p; }
  else if (which == 1) { XT = tvT; bias = bav_p; }
  else if (which == 2) { XT = xrT; bias = bek; }
  else                 { XT = xrT; bias = bev; }
  const u16* Wb = wkvb + (size_t)which * 65536;
  int t = threadIdx.x, w = t >> 6, l = t & 63, g = l >> 4, lq = l & 15;
  const u16* Xb = XT + (size_t)b * 65536;
  char* img = (char*)(KV + (size_t)(which * 64 + b * 8) * 8192);
  f32x4 acc[2][4];
#pragma unroll
  for (int ms = 0; ms < 2; ++ms)
#pragma unroll
    for (int ns = 0; ns < 4; ++ns) acc[ms][ns] = {0.f, 0.f, 0.f, 0.f};

  if (!(which & 1)) {
    // ---- K-type: acc rows along m (d), cols along n ----
#pragma unroll
    for (int k0 = 0; k0 < 256; k0 += 32) {
      FragU a[2], bb[4];
#pragma unroll
      for (int ms = 0; ms < 2; ++ms)
        a[ms].q = *(const uint4*)(Wb + (size_t)(m0 + ms * 16 + lq) * 256 + k0 + g * 8);
#pragma unroll
      for (int ns = 0; ns < 4; ++ns)
        bb[ns].q = *(const uint4*)(Xb + (size_t)(w * 64 + ns * 16 + lq) * 256 + k0 + g * 8);
#pragma unroll
      for (int ms = 0; ms < 2; ++ms)
#pragma unroll
        for (int ns = 0; ns < 4; ++ns)
          acc[ms][ns] = __builtin_amdgcn_mfma_f32_16x16x32_bf16(a[ms].v, bb[ns].v, acc[ms][ns], 0, 0, 0);
    }
    float bR[2][4];
#pragma unroll
    for (int ms = 0; ms < 2; ++ms)
#pragma unroll
      for (int r = 0; r < 4; ++r) bR[ms][r] = bias[m0 + ms * 16 + g * 4 + r];
#pragma unroll
    for (int ms = 0; ms < 2; ++ms) {
      int mm = m0 + ms * 16 + g * 4;
      int h = mm >> 5, d0 = mm & 31;
      int cb = (d0 >> 3) * 16, e0 = (d0 & 7) * 2;
#pragma unroll
      for (int ns = 0; ns < 4; ++ns) {
        int n = w * 64 + ns * 16 + lq;
        int off = ((n * 64 + cb) ^ (((n >> 1) & 7) << 4)) + e0;
        *(uint2*)(img + (size_t)h * 16384 + off) =
            make_uint2(pk2(acc[ms][ns][0] + bR[ms][0], acc[ms][ns][1] + bR[ms][1]),
                       pk2(acc[ms][ns][2] + bR[ms][2], acc[ms][ns][3] + bR[ms][3]));
      }
    }
  } else {
    // ---- V-type: operands swapped -> acc rows along n, cols along m (d) ----
#pragma unroll
    for (int k0 = 0; k0 < 256; k0 += 32) {
      FragU a[2], bb[4];
#pragma unroll
      for (int ms = 0; ms < 2; ++ms)
        a[ms].q = *(const uint4*)(Wb + (size_t)(m0 + ms * 16 + lq) * 256 + k0 + g * 8);
#pragma unroll
      for (int ns = 0; ns < 4; ++ns)
        bb[ns].q = *(const uint4*)(Xb + (size_t)(w * 64 + ns * 16 + lq) * 256 + k0 + g * 8);
#pragma unroll
      for (int ms = 0; ms < 2; ++ms)
#pragma unroll
        for (int ns = 0; ns < 4; ++ns)
          acc[ms][ns] = __builtin_amdgcn_mfma_f32_16x16x32_bf16(bb[ns].v, a[ms].v, acc[ms][ns], 0, 0, 0);
    }
    float bR[2];
#pragma unroll
    for (int ms = 0; ms < 2; ++ms) bR[ms] = bias[m0 + ms * 16 + lq];
#pragma unroll
    for (int ms = 0; ms < 2; ++ms) {
      int mm = m0 + ms * 16 + lq;
      int h = mm >> 5, d = mm & 31;
      int rowb = d * 512, swz = ((d >> 1) & 7) << 4;
#pragma unroll
      for (int ns = 0; ns < 4; ++ns) {
        int nn = w * 64 + ns * 16 + g * 4;
        int off = (rowb + nn * 2) ^ swz;
        *(uint2*)(img + (size_t)h * 16384 + off) =
            make_uint2(pk2(acc[ms][ns][0] + bR[ms], acc[ms][ns][1] + bR[ms]),
                       pk2(acc[ms][ns][2] + bR[ms], acc[ms][ns][3] + bR[ms]));
      }
    }
  }
}

// ---------------------------------------------------------------------------
// MFMA flash attention, 2 q-tiles per wave.  XCD-aware block swizzle (each
// XCD owns a contiguous 512-block chunk -> KV images + qb slices L2-local).
// Q loads before KV staging; global_load_lds staging; v_exp_f32 softmax;
// ones-MFMA denom; Olds aliases Ks; setprio.  grid (32, 8, 16), block 256.
// ---------------------------------------------------------------------------
__global__ __launch_bounds__(256) void k_attn_mfma(
    const u16* __restrict__ Qb, const u16* __restrict__ KV,
    u16* __restrict__ ObT) {
  int lid = blockIdx.x + 32 * (blockIdx.y + 8 * blockIdx.z);
  int swzid = (lid & 7) * 512 + (lid >> 3);
  int xq = swzid & 31, h = (swzid >> 5) & 7, z = swzid >> 8;
  int set = z >> 3, b = z & 7;
  __shared__ __align__(16) u16 Ks[8192];   // reused as Olds in epilogue
  __shared__ __align__(16) u16 Vt[8192];
  int t = threadIdx.x, w = t >> 6, l = t & 63;
  int lq = l & 15, g = l >> 4;
  int n0 = (xq << 7) + w * 32;

  // Q loads first: their latency hides under the KV staging wait.
  FragU qfA, qfB;
  const u16* qrow = Qb + ((size_t)(b * 16 + set * 8 + h) * 4096 + n0 + lq) * 32 + g * 8;
  qfA.q = *(const uint4*)(qrow);
  qfB.q = *(const uint4*)(qrow + 16 * 32);

  {
    const u16* kg = KV + (size_t)((set * 2 + 0) * 64 + b * 8 + h) * 8192;
    const u16* vg = KV + (size_t)((set * 2 + 1) * 64 + b * 8 + h) * 8192;
#pragma unroll
    for (int i = 0; i < 4; ++i) {
      gl16(kg + w * 2048 + i * 512 + l * 8, Ks + w * 2048 + i * 512);
      gl16(vg + w * 2048 + i * 512 + l * 8, Vt + w * 2048 + i * 512);
    }
    waitvm0();
  }
  __syncthreads();

  // QK read bases:  addr(kt even) = lbK + (kt>>1)*2048
  //                 addr(kt odd)  = (lbK^32) + 256 + (kt>>1)*2048
  int aA = lq >> 2, cC = lq & 3;
  int lbK = ((aA << 9) + (cC << 6) + (g << 4)) ^ ((cC >> 1) << 4) ^ ((aA & 1) << 6);
  const char* pe = (const char*)Ks + lbK;
  const char* po = (const char*)Ks + ((lbK ^ 32) + 256);

  unsigned pkuA[32], pkuB[32];
#pragma unroll
  for (int k2 = 0; k2 < 8; ++k2) {
    FragU af;
    f32x4 cA, cB;
    af.q = *(const uint4*)(pe + k2 * 2048);
    __builtin_amdgcn_s_setprio(1);
    cA = {0.f, 0.f, 0.f, 0.f};
    cA = __builtin_amdgcn_mfma_f32_16x16x32_bf16(af.v, qfA.v, cA, 0, 0, 0);
    cB = {0.f, 0.f, 0.f, 0.f};
    cB = __builtin_amdgcn_mfma_f32_16x16x32_bf16(af.v, qfB.v, cB, 0, 0, 0);
    __builtin_amdgcn_s_setprio(0);
    pkuA[4 * k2 + 0] = pk2(exp2r(cA[0]), exp2r(cA[1]));
    pkuA[4 * k2 + 1] = pk2(exp2r(cA[2]), exp2r(cA[3]));
    pkuB[4 * k2 + 0] = pk2(exp2r(cB[0]), exp2r(cB[1]));
    pkuB[4 * k2 + 1] = pk2(exp2r(cB[2]), exp2r(cB[3]));
    af.q = *(const uint4*)(po + k2 * 2048);
    __builtin_amdgcn_s_setprio(1);
    cA = {0.f, 0.f, 0.f, 0.f};
    cA = __builtin_amdgcn_mfma_f32_16x16x32_bf16(af.v, qfA.v, cA, 0, 0, 0);
    cB = {0.f, 0.f, 0.f, 0.f};
    cB = __builtin_amdgcn_mfma_f32_16x16x32_bf16(af.v, qfB.v, cB, 0, 0, 0);
    __builtin_amdgcn_s_setprio(0);
    pkuA[4 * k2 + 2] = pk2(exp2r(cA[0]), exp2r(cA[1]));
    pkuA[4 * k2 + 3] = pk2(exp2r(cA[2]), exp2r(cA[3]));
    pkuB[4 * k2 + 2] = pk2(exp2r(cB[0]), exp2r(cB[1]));
    pkuB[4 * k2 + 3] = pk2(exp2r(cB[2]), exp2r(cB[3]));
  }
  __syncthreads();  // all waves done reading Ks; it becomes Olds below

  // PV read bases: addr(kv even) = lbV + kb*64 + kv*64
  //                addr(kv odd)  = lbV - kb*64 + kv*64   (+8192 for row 16+lq)
  int lbV = (lq << 9) + ((g << 4) ^ ((lq & 6) << 3));
  int kb = (lq >> 3) & 1;
  const char* pp = (const char*)Vt + (lbV + kb * 64);
  const char* pm = (const char*)Vt + (lbV - kb * 64);

  FragU ones;
  ones.u[0] = ones.u[1] = ones.u[2] = ones.u[3] = 0x3F803F80u;
  f32x4 oA0 = {0.f, 0.f, 0.f, 0.f}, oA1 = {0.f, 0.f, 0.f, 0.f};
  f32x4 oB0 = {0.f, 0.f, 0.f, 0.f}, oB1 = {0.f, 0.f, 0.f, 0.f};
  f32x4 saA = {0.f, 0.f, 0.f, 0.f}, saB = {0.f, 0.f, 0.f, 0.f};
  __builtin_amdgcn_s_setprio(1);
#pragma unroll
  for (int kv = 0; kv < 8; ++kv) {
    FragU pbA, pbB;
    pbA.u[0] = pkuA[4 * kv + 0]; pbA.u[1] = pkuA[4 * kv + 1];
    pbA.u[2] = pkuA[4 * kv + 2]; pbA.u[3] = pkuA[4 * kv + 3];
    pbB.u[0] = pkuB[4 * kv + 0]; pbB.u[1] = pkuB[4 * kv + 1];
    pbB.u[2] = pkuB[4 * kv + 2]; pbB.u[3] = pkuB[4 * kv + 3];
    const char* pv = (kv & 1) ? pm : pp;
    FragU va0, va1;
    va0.q = *(const uint4*)(pv + kv * 64);
    va1.q = *(const uint4*)(pv + kv * 64 + 8192);
    oA0 = __builtin_amdgcn_mfma_f32_16x16x32_bf16(va0.v, pbA.v, oA0, 0, 0, 0);
    oA1 = __builtin_amdgcn_mfma_f32_16x16x32_bf16(va1.v, pbA.v, oA1, 0, 0, 0);
    oB0 = __builtin_amdgcn_mfma_f32_16x16x32_bf16(va0.v, pbB.v, oB0, 0, 0, 0);
    oB1 = __builtin_amdgcn_mfma_f32_16x16x32_bf16(va1.v, pbB.v, oB1, 0, 0, 0);
    saA = __builtin_amdgcn_mfma_f32_16x16x32_bf16(ones.v, pbA.v, saA, 0, 0, 0);
    saB = __builtin_amdgcn_mfma_f32_16x16x32_bf16(ones.v, pbB.v, saB, 0, 0, 0);
  }
  __builtin_amdgcn_s_setprio(0);

  float invA = __builtin_amdgcn_rcpf(saA[0]);  // all 4 rows identical = lsum
  float invB = __builtin_amdgcn_rcpf(saB[0]);
  {
    char* ob = (char*)Ks;  // Olds: 128 rows x 80B
    int nnA = w * 32 + lq, nnB = nnA + 16;
    *(uint2*)(ob + nnA * 80 + g * 8) =
        make_uint2(pk2(oA0[0] * invA, oA0[1] * invA), pk2(oA0[2] * invA, oA0[3] * invA));
    *(uint2*)(ob + nnA * 80 + 32 + g * 8) =
        make_uint2(pk2(oA1[0] * invA, oA1[1] * invA), pk2(oA1[2] * invA, oA1[3] * invA));
    *(uint2*)(ob + nnB * 80 + g * 8) =
        make_uint2(pk2(oB0[0] * invB, oB0[1] * invB), pk2(oB0[2] * invB, oB0[3] * invB));
    *(uint2*)(ob + nnB * 80 + 32 + g * 8) =
        make_uint2(pk2(oB1[0] * invB, oB1[1] * invB), pk2(oB1[2] * invB, oB1[3] * invB));
  }
  __syncthreads();
#pragma unroll
  for (int rep = 0; rep < 2; ++rep) {
    int idx = rep * 256 + t;
    int nn = idx >> 2, dq = idx & 3;
    uint4 v = *(const uint4*)((const char*)Ks + nn * 80 + dq * 16);
    *(uint4*)(ObT + ((size_t)b * 4096 + (xq << 7) + nn) * 512 +
              set * 256 + h * 32 + dq * 8) = v;
  }
}

// ---------------------------------------------------------------------------
// Output projection: 128x128-tile 2-phase LDS-staged MFMA GEMM (R8 config).
// out = wproj(256x512) x ObT^T + bias, fp32.  grid (32 n, 2 m, 8 b), blk 256.
// ---------------------------------------------------------------------------
__global__ __launch_bounds__(256) void k_gemm_proj(
    const u16* __restrict__ XT, const u16* __restrict__ Wb,
    const float* __restrict__ bias, float* __restrict__ Y) {
  __shared__ __align__(16) u16 SM[16384];
  int n0 = blockIdx.x * 128, m0 = blockIdx.y * 128, b = blockIdx.z;
  int t = threadIdx.x, w = t >> 6, l = t & 63, g = l >> 4, lq = l & 15;
  int wr = w >> 1, wc = w & 1;
  const u16* Xb = XT + (size_t)b * 4096 * 512;
  int srow = w * 32 + (l >> 2), scol = (l & 3) * 8;
  const u16* gA = Wb + (size_t)(m0 + srow) * 512 + scol;
  const u16* gB = Xb + (size_t)(n0 + srow) * 512 + scol;
  u16* lA = SM + w * 1024;
  u16* lB = SM + 8192 + w * 1024;

  f32x4 acc[4][4];
#pragma unroll
  for (int ms = 0; ms < 4; ++ms)
#pragma unroll
    for (int ns = 0; ns < 4; ++ns) acc[ms][ns] = {0.f, 0.f, 0.f, 0.f};

  gl16(gA, lA); gl16(gA + 16 * 512, lA + 512);
  gl16(gB, lB); gl16(gB + 16 * 512, lB + 512);
  waitvm0();
  __syncthreads();
#pragma unroll
  for (int kt = 0; kt < 16; ++kt) {
    int cur = kt & 1;
    if (kt < 15) {
      int sel = cur ^ 1, ko = (kt + 1) * 32;
      gl16(gA + ko, lA + sel * 4096); gl16(gA + 16 * 512 + ko, lA + sel * 4096 + 512);
      gl16(gB + ko, lB + sel * 4096); gl16(gB + 16 * 512 + ko, lB + sel * 4096 + 512);
    }
    const u16* Ab = SM + cur * 4096;
    const u16* Bb = SM + 8192 + cur * 4096;
    FragU a[4], bb[4];
#pragma unroll
    for (int ms = 0; ms < 4; ++ms)
      a[ms].q = *(const uint4*)(Ab + (wr * 64 + ms * 16 + lq) * 32 + g * 8);
#pragma unroll
    for (int ns = 0; ns < 4; ++ns)
      bb[ns].q = *(const uint4*)(Bb + (wc * 64 + ns * 16 + lq) * 32 + g * 8);
#pragma unroll
    for (int ms = 0; ms < 4; ++ms)
#pragma unroll
      for (int ns = 0; ns < 4; ++ns)
        acc[ms][ns] = __builtin_amdgcn_mfma_f32_16x16x32_bf16(a[ms].v, bb[ns].v, acc[ms][ns], 0, 0, 0);
    waitvm0();
    __syncthreads();
  }
#pragma unroll
  for (int ms = 0; ms < 4; ++ms)
#pragma unroll
    for (int ns = 0; ns < 4; ++ns) {
      int n = n0 + wc * 64 + ns * 16 + lq;
#pragma unroll
      for (int r = 0; r < 4; ++r) {
        int m = m0 + wr * 64 + ms * 16 + g * 4 + r;
        Y[((size_t)b * 256 + m) * 4096 + n] = acc[ms][ns][r] + bias[m];
      }
    }
}

// ---------------------------------------------------------------------------

extern "C" void kernel_launch(void* const* d_in, const int* in_sizes, int n_in,
                              void* d_out, int out_size, void* d_ws, size_t ws_size,
                              hipStream_t stream) {
  (void)in_sizes; (void)n_in; (void)out_size; (void)ws_size;
  const float* x     = (const float*)d_in[0];
  const float* wq    = (const float*)d_in[1];
  const float* bq    = (const float*)d_in[2];
  const float* wsw   = (const float*)d_in[3];
  const float* bs    = (const float*)d_in[4];
  const float* wak_d = (const float*)d_in[5];
  const float* bak_d = (const float*)d_in[6];
  const float* wak_p = (const float*)d_in[7];
  const float* bak_p = (const float*)d_in[8];
  const float* wav_d = (const float*)d_in[9];
  const float* bav_d = (const float*)d_in[10];
  const float* wav_p = (const float*)d_in[11];
  const float* bav_p = (const float*)d_in[12];
  const float* wek   = (const float*)d_in[13];
  const float* bek   = (const float*)d_in[14];
  const float* wev   = (const float*)d_in[15];
  const float* bev   = (const float*)d_in[16];
  const float* wproj = (const float*)d_in[17];
  const float* bproj = (const float*)d_in[18];
  float* out = (float*)d_out;

  char* p = (char*)d_ws;
  u16* xbT  = (u16*)p;   p += (size_t)8 * 4096 * 256 * 2;     // 16.8 MB
  u16* qb   = (u16*)p;   p += (size_t)8 * 16 * 4096 * 32 * 2; // 33.6 MB
  u16* obT  = (u16*)p;   p += (size_t)8 * 4096 * 512 * 2;     // 33.6 MB
  float* xr  = (float*)p; p += (size_t)524288 * 4;            // 2.1 MB
  u16* xrT  = (u16*)p;   p += (size_t)524288 * 2;
  u16* tkT  = (u16*)p;   p += (size_t)524288 * 2;
  u16* tvT  = (u16*)p;   p += (size_t)524288 * 2;
  u16* kvimg = (u16*)p;  p += (size_t)4 * 64 * 8192 * 2;      // 4.2 MB
  u16* wqb  = (u16*)p;   p += (size_t)131072 * 2;
  u16* wpb  = (u16*)p;   p += (size_t)131072 * 2;
  u16* wsb  = (u16*)p;   p += (size_t)1048576 * 2;
  u16* wkvb = (u16*)p;   p += (size_t)262144 * 2;

  k_xT<<<dim3(64, 8, 9), 256, 0, stream>>>(x, xbT, wq, wproj, wsw,
                                           wak_p, wav_p, wek, wev,
                                           wqb, wpb, wsb, wkvb, xr);
  k_gemm_x<<<dim3(40, 4, 8), 256, 0, stream>>>(xbT, wqb, bq, qb, wsb, xr);
  k_srdw<<<dim3(16, 8), 256, 0, stream>>>(xr, bs, wak_d, bak_d, wav_d, bav_d,
                                          xrT, tkT, tvT);
  k_gemm_kv<<<dim3(4, 8, 8), 256, 0, stream>>>(xrT, tkT, tvT, wkvb,
                                               bak_p, bav_p, bek, bev, kvimg);
  k_attn_mfma<<<dim3(32, 8, 16), 256, 0, stream>>>(qb, kvimg, obT);
  k_gemm_proj<<<dim3(32, 2, 8), 256, 0, stream>>>(obT, wpb, bproj, out);
}

// Round 12
// 119.047 us; speedup vs baseline: 1.0433x; 1.0433x over previous
//
#include <hip/hip_runtime.h>
#include <hip/hip_bf16.h>

// HD^-0.5 * log2(e): scores scaled so softmax uses exp2 directly.
#define QSC (0.17677669529663687f * 1.4426950408889634f)

typedef __attribute__((ext_vector_type(8))) short bf16x8;
typedef __attribute__((ext_vector_type(4))) float f32x4;
typedef unsigned short u16;

union FragU { unsigned u[4]; uint4 q; bf16x8 v; };

__device__ inline u16 f2bu(float a) {
  union { __hip_bfloat16 h; u16 s; } c;
  c.h = __float2bfloat16(a);
  return c.s;
}
// Single-instruction packed f32->bf16 (RNE): lo -> low 16, hi -> high 16.
__device__ inline unsigned pk2(float lo, float hi) {
  unsigned r;
  asm("v_cvt_pk_bf16_f32 %0, %1, %2" : "=v"(r) : "v"(lo), "v"(hi));
  return r;
}
// Raw v_exp_f32 (2^x). Scores are O(1): no subnormal fixup needed.
__device__ inline float exp2r(float x) {
  float r;
  asm("v_exp_f32 %0, %1" : "=v"(r) : "v"(x));
  return r;
}
// Async global->LDS, 16B per lane. LDS dest is wave-uniform base + lane*16.
__device__ inline void gl16(const u16* g, u16* l) {
  __builtin_amdgcn_global_load_lds(
      (const __attribute__((address_space(1))) unsigned int*)g,
      (__attribute__((address_space(3))) unsigned int*)l, 16, 0, 0);
}
__device__ inline void waitvm0() {
  asm volatile("s_waitcnt vmcnt(0)" ::: "memory");
}

// ---------------------------------------------------------------------------
// x transpose+convert: xbT[b][n(4096)][c(256)] bf16 from x[b][c][n] f32.
// grid (64 nchunk, 8 cchunk, 9), block 256.  z==8 plane does weight prep
// (bf16 conversion; ws k-reordered to [co][tap*256+ci]).
// ---------------------------------------------------------------------------
__global__ __launch_bounds__(256) void k_xT(
    const float* __restrict__ X, u16* __restrict__ XT,
    const float* __restrict__ wq, const float* __restrict__ wproj,
    const float* __restrict__ ws,
    const float* __restrict__ w0, const float* __restrict__ w1,
    const float* __restrict__ w2, const float* __restrict__ w3,
    u16* __restrict__ wqb, u16* __restrict__ wpb,
    u16* __restrict__ wsb, u16* __restrict__ wkvb) {
  if (blockIdx.z == 8) {
    int which = blockIdx.y;
    int tid = blockIdx.x * 256 + threadIdx.x;  // 0..16383
    const int ST = 16384;
    if (which == 0) {
      for (int i = tid; i < 131072; i += ST) wqb[i] = f2bu(wq[i]);
    } else if (which == 1) {
      for (int i = tid; i < 131072; i += ST) wpb[i] = f2bu(wproj[i]);
    } else if (which == 2) {
      for (int i = tid; i < 1048576; i += ST) {
        int co = i >> 12, rem = i & 4095, tap = rem >> 8, ci = rem & 255;
        wsb[i] = f2bu(ws[co * 4096 + ci * 16 + tap]);
      }
    } else if (which < 7) {
      const float* src = (which == 3) ? w0 : (which == 4) ? w1 : (which == 5) ? w2 : w3;
      u16* dst = wkvb + (size_t)(which - 3) * 65536;
      for (int i = tid; i < 65536; i += ST) dst[i] = f2bu(src[i]);
    }
    return;
  }
  __shared__ float L[32 * 65];
  int n0 = blockIdx.x * 64, c0 = blockIdx.y * 32, b = blockIdx.z;
  int t = threadIdx.x;
#pragma unroll
  for (int i = 0; i < 8; ++i) {
    int idx = i * 256 + t;
    int r = idx >> 6, nn = idx & 63;
    L[r * 65 + nn] = X[((size_t)(b * 256 + c0 + r)) * 4096 + n0 + nn];
  }
  __syncthreads();
  int nn = t >> 2, cq = t & 3;
  uint4 u;
  u.x = pk2(L[(cq * 8 + 0) * 65 + nn], L[(cq * 8 + 1) * 65 + nn]);
  u.y = pk2(L[(cq * 8 + 2) * 65 + nn], L[(cq * 8 + 3) * 65 + nn]);
  u.z = pk2(L[(cq * 8 + 4) * 65 + nn], L[(cq * 8 + 5) * 65 + nn]);
  u.w = pk2(L[(cq * 8 + 6) * 65 + nn], L[(cq * 8 + 7) * 65 + nn]);
  *(uint4*)(XT + ((size_t)b * 4096 + n0 + nn) * 256 + c0 + cq * 8) = u;
}

// ---------------------------------------------------------------------------
// FUSED qproj + sr GEMM (R8 structure: 2-phase gl16 staging, vmcnt(0)+
// __syncthreads per K-step).  blockIdx.x < 32: qproj tile; else sr K-split
// ks = blockIdx.x-32 -> psr partials.  grid (40, 4, 8), block 256.
// ---------------------------------------------------------------------------
__global__ __launch_bounds__(256) void k_gemm_x(
    const u16* __restrict__ XT, const u16* __restrict__ Wqb,
    const float* __restrict__ bias, u16* __restrict__ Qb,
    const u16* __restrict__ Wsb, float* __restrict__ Psr) {
  __shared__ __align__(16) u16 SM[16384];  // As[2][4096] | Bs[2][4096]
  int b = blockIdx.z;
  int t = threadIdx.x, w = t >> 6, l = t & 63, g = l >> 4, lq = l & 15;
  int wr = w >> 1, wc = w & 1;
  const u16* Xb = XT + (size_t)b * 4096 * 256;
  int srow = w * 32 + (l >> 2), scol = (l & 3) * 8;
  u16* lA = SM + w * 1024;         // wave-uniform staging bases
  u16* lB = SM + 8192 + w * 1024;

  f32x4 acc[4][4];
#pragma unroll
  for (int ms = 0; ms < 4; ++ms)
#pragma unroll
    for (int ns = 0; ns < 4; ++ns) acc[ms][ns] = {0.f, 0.f, 0.f, 0.f};

  if (blockIdx.x < 32) {
    // ================= qproj path =================
    int n0 = blockIdx.x * 128, m0 = blockIdx.y * 128;
    const u16* gA = Wqb + (size_t)(m0 + srow) * 256 + scol;
    const u16* gB = Xb + (size_t)(n0 + srow) * 256 + scol;

    gl16(gA, lA); gl16(gA + 16 * 256, lA + 512);
    gl16(gB, lB); gl16(gB + 16 * 256, lB + 512);
    waitvm0();
    __syncthreads();
#pragma unroll
    for (int kt = 0; kt < 8; ++kt) {
      int cur = kt & 1;
      if (kt < 7) {
        int sel = cur ^ 1, ko = (kt + 1) * 32;
        gl16(gA + ko, lA + sel * 4096); gl16(gA + 16 * 256 + ko, lA + sel * 4096 + 512);
        gl16(gB + ko, lB + sel * 4096); gl16(gB + 16 * 256 + ko, lB + sel * 4096 + 512);
      }
      const u16* Ab = SM + cur * 4096;
      const u16* Bb = SM + 8192 + cur * 4096;
      FragU a[4], bb[4];
#pragma unroll
      for (int ms = 0; ms < 4; ++ms)
        a[ms].q = *(const uint4*)(Ab + (wr * 64 + ms * 16 + lq) * 32 + g * 8);
#pragma unroll
      for (int ns = 0; ns < 4; ++ns)
        bb[ns].q = *(const uint4*)(Bb + (wc * 64 + ns * 16 + lq) * 32 + g * 8);
#pragma unroll
      for (int ms = 0; ms < 4; ++ms)
#pragma unroll
        for (int ns = 0; ns < 4; ++ns)
          acc[ms][ns] = __builtin_amdgcn_mfma_f32_16x16x32_bf16(a[ms].v, bb[ns].v, acc[ms][ns], 0, 0, 0);
      waitvm0();
      __syncthreads();
    }

    float bR[4][4];
#pragma unroll
    for (int ms = 0; ms < 4; ++ms)
#pragma unroll
      for (int r = 0; r < 4; ++r) bR[ms][r] = bias[m0 + wr * 64 + ms * 16 + g * 4 + r];

    // epilogue: acc -> LDS [n_local(128)][m_local(128)] u16 (XOR-swizzled),
    // then coalesced 16B stores to qb attn layout.
    char* Lc = (char*)SM;
#pragma unroll
    for (int ms = 0; ms < 4; ++ms)
#pragma unroll
      for (int ns = 0; ns < 4; ++ns) {
        int nl = wc * 64 + ns * 16 + lq;
        int mb2 = (wr * 64 + ms * 16 + g * 4) * 2;
        int off = (nl * 256 + mb2) ^ ((nl & 7) << 4);
        *(uint2*)(Lc + off) = make_uint2(
            pk2((acc[ms][ns][0] + bR[ms][0]) * QSC, (acc[ms][ns][1] + bR[ms][1]) * QSC),
            pk2((acc[ms][ns][2] + bR[ms][2]) * QSC, (acc[ms][ns][3] + bR[ms][3]) * QSC));
      }
    __syncthreads();
    int sh0 = m0 >> 5;
#pragma unroll
    for (int rr = 0; rr < 8; ++rr) {
      int idx = rr * 256 + t;
      int ch = idx & 3, shl = (idx >> 2) & 3, nn = idx >> 4;
      int off = (nn * 256 + shl * 64 + ch * 16) ^ ((nn & 7) << 4);
      uint4 v = *(const uint4*)(Lc + off);
      *(uint4*)(Qb + ((size_t)(b * 16 + sh0 + shl) * 4096 + n0 + nn) * 32 + ch * 8) = v;
    }
  } else {
    // ================= sr path (K-split by 8) =================
    int ks = blockIdx.x - 32;
    int m0 = (blockIdx.y >> 1) * 128, n0 = (blockIdx.y & 1) * 128;
    const u16* gA = Wsb + (size_t)(m0 + srow) * 4096 + scol;
    int nA = n0 + srow, nB = nA + 16;
    int iA = nA >> 4, jA = nA & 15, iB = nB >> 4, jB = nB & 15;

#define SR_STAGE(sel, kt) {                                                   \
    int ktg = ks * 16 + (kt);                                                 \
    int tap = ktg >> 3, ci0 = (ktg & 7) * 32;                                 \
    int ky = tap >> 2, kx = tap & 3;                                          \
    gl16(gA + ktg * 32, lA + (sel) * 4096);                                   \
    gl16(gA + (size_t)16 * 4096 + ktg * 32, lA + (sel) * 4096 + 512);         \
    int pixA = (4 * iA + ky) * 64 + 4 * jA + kx;                              \
    int pixB = (4 * iB + ky) * 64 + 4 * jB + kx;                              \
    gl16(Xb + (size_t)pixA * 256 + ci0 + scol, lB + (sel) * 4096);            \
    gl16(Xb + (size_t)pixB * 256 + ci0 + scol, lB + (sel) * 4096 + 512); }

    SR_STAGE(0, 0);
    waitvm0();
    __syncthreads();
#pragma unroll
    for (int kt = 0; kt < 16; ++kt) {
      int cur = kt & 1;
      if (kt < 15) SR_STAGE(cur ^ 1, kt + 1);
      const u16* Ab = SM + cur * 4096;
      const u16* Bb = SM + 8192 + cur * 4096;
      FragU a[4], bb[4];
#pragma unroll
      for (int ms = 0; ms < 4; ++ms)
        a[ms].q = *(const uint4*)(Ab + (wr * 64 + ms * 16 + lq) * 32 + g * 8);
#pragma unroll
      for (int ns = 0; ns < 4; ++ns)
        bb[ns].q = *(const uint4*)(Bb + (wc * 64 + ns * 16 + lq) * 32 + g * 8);
#pragma unroll
      for (int ms = 0; ms < 4; ++ms)
#pragma unroll
        for (int ns = 0; ns < 4; ++ns)
          acc[ms][ns] = __builtin_amdgcn_mfma_f32_16x16x32_bf16(a[ms].v, bb[ns].v, acc[ms][ns], 0, 0, 0);
      waitvm0();
      __syncthreads();
    }
#undef SR_STAGE
#pragma unroll
    for (int ms = 0; ms < 4; ++ms)
#pragma unroll
      for (int ns = 0; ns < 4; ++ns) {
        int n = n0 + wc * 64 + ns * 16 + lq;
#pragma unroll
        for (int r = 0; r < 4; ++r) {
          int m = m0 + wr * 64 + ms * 16 + g * 4 + r;
          Psr[(((size_t)ks * 8 + b) * 256 + m) * 256 + n] = acc[ms][ns][r];
        }
      }
  }
}

// ---------------------------------------------------------------------------
// Fused: reduce sr partials (+bias) -> LDS; emit xrT bf16 [b][pix][c] AND
// depthwise 3x3 -> tkT/tvT bf16 [b][pix][c].  16 channels/block (128 blocks
// -> better CU coverage).  grid (16 cg, 8 b), block 256 = pixels.
// ---------------------------------------------------------------------------
__global__ __launch_bounds__(256) void k_srdw(
    const float* __restrict__ Psr, const float* __restrict__ bias,
    const float* __restrict__ wkd, const float* __restrict__ bkd,
    const float* __restrict__ wvd, const float* __restrict__ bvd,
    u16* __restrict__ xrT, u16* __restrict__ TKt, u16* __restrict__ TVt) {
  __shared__ float L[16 * 256];
  int cg = blockIdx.x, b = blockIdx.y, t = threadIdx.x;
#pragma unroll
  for (int r = 0; r < 16; ++r) {
    int c = cg * 16 + r;
    float s = bias[c];
#pragma unroll
    for (int ks = 0; ks < 8; ++ks)
      s += Psr[(((size_t)ks * 8 + b) * 256 + c) * 256 + t];
    L[r * 256 + t] = s;
  }
  __syncthreads();
  {
    unsigned wv[8];
#pragma unroll
    for (int r2 = 0; r2 < 8; ++r2)
      wv[r2] = pk2(L[(2 * r2) * 256 + t], L[(2 * r2 + 1) * 256 + t]);
    u16* dst = xrT + ((size_t)b * 256 + t) * 256 + cg * 16;
    *(uint4*)(dst + 0) = make_uint4(wv[0], wv[1], wv[2], wv[3]);
    *(uint4*)(dst + 8) = make_uint4(wv[4], wv[5], wv[6], wv[7]);
  }
  int i = t >> 4, j = t & 15;
  unsigned wk[8], wvv[8];
#pragma unroll
  for (int r2 = 0; r2 < 8; ++r2) {
    int c0 = cg * 16 + 2 * r2;
    float ak0 = bkd[c0], ak1 = bkd[c0 + 1];
    float av0 = bvd[c0], av1 = bvd[c0 + 1];
#pragma unroll
    for (int ky = 0; ky < 3; ++ky) {
      int ii = i + ky - 1;
      if (ii < 0 || ii > 15) continue;
#pragma unroll
      for (int kx = 0; kx < 3; ++kx) {
        int jj = j + kx - 1;
        if (jj < 0 || jj > 15) continue;
        float v0 = L[(2 * r2) * 256 + ii * 16 + jj];
        float v1 = L[(2 * r2 + 1) * 256 + ii * 16 + jj];
        float wk0 = wkd[c0 * 9 + ky * 3 + kx], wk1 = wkd[(c0 + 1) * 9 + ky * 3 + kx];
        float wv0 = wvd[c0 * 9 + ky * 3 + kx], wv1 = wvd[(c0 + 1) * 9 + ky * 3 + kx];
        ak0 = fmaf(v0, wk0, ak0); ak1 = fmaf(v1, wk1, ak1);
        av0 = fmaf(v0, wv0, av0); av1 = fmaf(v1, wv1, av1);
      }
    }
    wk[r2] = pk2(ak0, ak1);
    wvv[r2] = pk2(av0, av1);
  }
  u16* dk = TKt + ((size_t)b * 256 + t) * 256 + cg * 16;
  u16* dv = TVt + ((size_t)b * 256 + t) * 256 + cg * 16;
  *(uint4*)(dk + 0) = make_uint4(wk[0], wk[1], wk[2], wk[3]);
  *(uint4*)(dk + 8) = make_uint4(wk[4], wk[5], wk[6], wk[7]);
  *(uint4*)(dv + 0) = make_uint4(wvv[0], wvv[1], wvv[2], wvv[3]);
  *(uint4*)(dv + 8) = make_uint4(wvv[4], wvv[5], wvv[6], wvv[7]);
}

// ---------------------------------------------------------------------------
// K/V pointwise projections as MFMA GEMM -> bf16 pre-swizzled 16KB LDS
// images, one per (which, b, h):  KV[(which*64 + b*8 + h)*8192 u16].
//   K image byte: ((n*64 + (d>>3)*16) ^ (((n>>1)&7)<<4)) + (d&7)*2
//   V image byte:  (d*512 + n*2)      ^ (((d>>1)&7)<<4)
// grid (4 which, 8 m, 8 b) = 256 blocks (1/CU).
// ---------------------------------------------------------------------------
__global__ __launch_bounds__(256) void k_gemm_kv(
    const u16* __restrict__ xrT, const u16* __restrict__ tkT, const u16* __restrict__ tvT,
    const u16* __restrict__ wkvb,
    const float* __restrict__ bak_p, const float* __restrict__ bav_p,
    const float* __restrict__ bek, const float* __restrict__ bev,
    u16* __restrict__ KV) {
  int which = blockIdx.x, m0 = blockIdx.y * 32, b = blockIdx.z;
  const u16* XT; const float* bias;
  if (which == 0)      { XT = tkT; bias = bak_p; }
  else if (which == 1) { XT = tvT; bias = bav_p; }
  else if (which == 2) { XT = xrT; bias = bek; }
  else                 { XT = xrT; bias = bev; }
  const u16* Wb = wkvb + (size_t)which * 65536;
  int t = threadIdx.x, w = t >> 6, l = t & 63, g = l >> 4, lq = l & 15;
  const u16* Xb = XT + (size_t)b * 65536;
  char* img = (char*)(KV + (size_t)(which * 64 + b * 8) * 8192);
  f32x4 acc[2][4];
#pragma unroll
  for (int ms = 0; ms < 2; ++ms)
#pragma unroll
    for (int ns = 0; ns < 4; ++ns) acc[ms][ns] = {0.f, 0.f, 0.f, 0.f};

  if (!(which & 1)) {
    // ---- K-type: acc rows along m (d), cols along n ----
#pragma unroll
    for (int k0 = 0; k0 < 256; k0 += 32) {
      FragU a[2], bb[4];
#pragma unroll
      for (int ms = 0; ms < 2; ++ms)
        a[ms].q = *(const uint4*)(Wb + (size_t)(m0 + ms * 16 + lq) * 256 + k0 + g * 8);
#pragma unroll
      for (int ns = 0; ns < 4; ++ns)
        bb[ns].q = *(const uint4*)(Xb + (size_t)(w * 64 + ns * 16 + lq) * 256 + k0 + g * 8);
#pragma unroll
      for (int ms = 0; ms < 2; ++ms)
#pragma unroll
        for (int ns = 0; ns < 4; ++ns)
          acc[ms][ns] = __builtin_amdgcn_mfma_f32_16x16x32_bf16(a[ms].v, bb[ns].v, acc[ms][ns], 0, 0, 0);
    }
    float bR[2][4];
#pragma unroll
    for (int ms = 0; ms < 2; ++ms)
#pragma unroll
      for (int r = 0; r < 4; ++r) bR[ms][r] = bias[m0 + ms * 16 + g * 4 + r];
#pragma unroll
    for (int ms = 0; ms < 2; ++ms) {
      int mm = m0 + ms * 16 + g * 4;
      int h = mm >> 5, d0 = mm & 31;
      int cb = (d0 >> 3) * 16, e0 = (d0 & 7) * 2;
#pragma unroll
      for (int ns = 0; ns < 4; ++ns) {
        int n = w * 64 + ns * 16 + lq;
        int off = ((n * 64 + cb) ^ (((n >> 1) & 7) << 4)) + e0;
        *(uint2*)(img + (size_t)h * 16384 + off) =
            make_uint2(pk2(acc[ms][ns][0] + bR[ms][0], acc[ms][ns][1] + bR[ms][1]),
                       pk2(acc[ms][ns][2] + bR[ms][2], acc[ms][ns][3] + bR[ms][3]));
      }
    }
  } else {
    // ---- V-type: operands swapped -> acc rows along n, cols along m (d) ----
#pragma unroll
    for (int k0 = 0; k0 < 256; k0 += 32) {
      FragU a[2], bb[4];
#pragma unroll
      for (int ms = 0; ms < 2; ++ms)
        a[ms].q = *(const uint4*)(Wb + (size_t)(m0 + ms * 16 + lq) * 256 + k0 + g * 8);
#pragma unroll
      for (int ns = 0; ns < 4; ++ns)
        bb[ns].q = *(const uint4*)(Xb + (size_t)(w * 64 + ns * 16 + lq) * 256 + k0 + g * 8);
#pragma unroll
      for (int ms = 0; ms < 2; ++ms)
#pragma unroll
        for (int ns = 0; ns < 4; ++ns)
          acc[ms][ns] = __builtin_amdgcn_mfma_f32_16x16x32_bf16(bb[ns].v, a[ms].v, acc[ms][ns], 0, 0, 0);
    }
    float bR[2];
#pragma unroll
    for (int ms = 0; ms < 2; ++ms) bR[ms] = bias[m0 + ms * 16 + lq];
#pragma unroll
    for (int ms = 0; ms < 2; ++ms) {
      int mm = m0 + ms * 16 + lq;
      int h = mm >> 5, d = mm & 31;
      int rowb = d * 512, swz = ((d >> 1) & 7) << 4;
#pragma unroll
      for (int ns = 0; ns < 4; ++ns) {
        int nn = w * 64 + ns * 16 + g * 4;
        int off = (rowb + nn * 2) ^ swz;
        *(uint2*)(img + (size_t)h * 16384 + off) =
            make_uint2(pk2(acc[ms][ns][0] + bR[ms], acc[ms][ns][1] + bR[ms]),
                       pk2(acc[ms][ns][2] + bR[ms], acc[ms][ns][3] + bR[ms]));
      }
    }
  }
}

// ---------------------------------------------------------------------------
// MFMA flash attention, 2 q-tiles per wave.  XCD-aware block swizzle (each
// XCD owns a contiguous 512-block chunk -> KV images + qb slices L2-local).
// Q loads before KV staging; global_load_lds staging; v_exp_f32 softmax;
// ones-MFMA denom; Olds aliases Ks; setprio.  grid (32, 8, 16), block 256.
// ---------------------------------------------------------------------------
__global__ __launch_bounds__(256) void k_attn_mfma(
    const u16* __restrict__ Qb, const u16* __restrict__ KV,
    u16* __restrict__ ObT) {
  int lid = blockIdx.x + 32 * (blockIdx.y + 8 * blockIdx.z);
  int swzid = (lid & 7) * 512 + (lid >> 3);
  int xq = swzid & 31, h = (swzid >> 5) & 7, z = swzid >> 8;
  int set = z >> 3, b = z & 7;
  __shared__ __align__(16) u16 Ks[8192];   // reused as Olds in epilogue
  __shared__ __align__(16) u16 Vt[8192];
  int t = threadIdx.x, w = t >> 6, l = t & 63;
  int lq = l & 15, g = l >> 4;
  int n0 = (xq << 7) + w * 32;

  // Q loads first: their latency hides under the KV staging wait.
  FragU qfA, qfB;
  const u16* qrow = Qb + ((size_t)(b * 16 + set * 8 + h) * 4096 + n0 + lq) * 32 + g * 8;
  qfA.q = *(const uint4*)(qrow);
  qfB.q = *(const uint4*)(qrow + 16 * 32);

  {
    const u16* kg = KV + (size_t)((set * 2 + 0) * 64 + b * 8 + h) * 8192;
    const u16* vg = KV + (size_t)((set * 2 + 1) * 64 + b * 8 + h) * 8192;
#pragma unroll
    for (int i = 0; i < 4; ++i) {
      gl16(kg + w * 2048 + i * 512 + l * 8, Ks + w * 2048 + i * 512);
      gl16(vg + w * 2048 + i * 512 + l * 8, Vt + w * 2048 + i * 512);
    }
    waitvm0();
  }
  __syncthreads();

  // QK read bases:  addr(kt even) = lbK + (kt>>1)*2048
  //                 addr(kt odd)  = (lbK^32) + 256 + (kt>>1)*2048
  int aA = lq >> 2, cC = lq & 3;
  int lbK = ((aA << 9) + (cC << 6) + (g << 4)) ^ ((cC >> 1) << 4) ^ ((aA & 1) << 6);
  const char* pe = (const char*)Ks + lbK;
  const char* po = (const char*)Ks + ((lbK ^ 32) + 256);

  unsigned pkuA[32], pkuB[32];
#pragma unroll
  for (int k2 = 0; k2 < 8; ++k2) {
    FragU af;
    f32x4 cA, cB;
    af.q = *(const uint4*)(pe + k2 * 2048);
    __builtin_amdgcn_s_setprio(1);
    cA = {0.f, 0.f, 0.f, 0.f};
    cA = __builtin_amdgcn_mfma_f32_16x16x32_bf16(af.v, qfA.v, cA, 0, 0, 0);
    cB = {0.f, 0.f, 0.f, 0.f};
    cB = __builtin_amdgcn_mfma_f32_16x16x32_bf16(af.v, qfB.v, cB, 0, 0, 0);
    __builtin_amdgcn_s_setprio(0);
    pkuA[4 * k2 + 0] = pk2(exp2r(cA[0]), exp2r(cA[1]));
    pkuA[4 * k2 + 1] = pk2(exp2r(cA[2]), exp2r(cA[3]));
    pkuB[4 * k2 + 0] = pk2(exp2r(cB[0]), exp2r(cB[1]));
    pkuB[4 * k2 + 1] = pk2(exp2r(cB[2]), exp2r(cB[3]));
    af.q = *(const uint4*)(po + k2 * 2048);
    __builtin_amdgcn_s_setprio(1);
    cA = {0.f, 0.f, 0.f, 0.f};
    cA = __builtin_amdgcn_mfma_f32_16x16x32_bf16(af.v, qfA.v, cA, 0, 0, 0);
    cB = {0.f, 0.f, 0.f, 0.f};
    cB = __builtin_amdgcn_mfma_f32_16x16x32_bf16(af.v, qfB.v, cB, 0, 0, 0);
    __builtin_amdgcn_s_setprio(0);
    pkuA[4 * k2 + 2] = pk2(exp2r(cA[0]), exp2r(cA[1]));
    pkuA[4 * k2 + 3] = pk2(exp2r(cA[2]), exp2r(cA[3]));
    pkuB[4 * k2 + 2] = pk2(exp2r(cB[0]), exp2r(cB[1]));
    pkuB[4 * k2 + 3] = pk2(exp2r(cB[2]), exp2r(cB[3]));
  }
  __syncthreads();  // all waves done reading Ks; it becomes Olds below

  // PV read bases: addr(kv even) = lbV + kb*64 + kv*64
  //                addr(kv odd)  = lbV - kb*64 + kv*64   (+8192 for row 16+lq)
  int lbV = (lq << 9) + ((g << 4) ^ ((lq & 6) << 3));
  int kb = (lq >> 3) & 1;
  const char* pp = (const char*)Vt + (lbV + kb * 64);
  const char* pm = (const char*)Vt + (lbV - kb * 64);

  FragU ones;
  ones.u[0] = ones.u[1] = ones.u[2] = ones.u[3] = 0x3F803F80u;
  f32x4 oA0 = {0.f, 0.f, 0.f, 0.f}, oA1 = {0.f, 0.f, 0.f, 0.f};
  f32x4 oB0 = {0.f, 0.f, 0.f, 0.f}, oB1 = {0.f, 0.f, 0.f, 0.f};
  f32x4 saA = {0.f, 0.f, 0.f, 0.f}, saB = {0.f, 0.f, 0.f, 0.f};
  __builtin_amdgcn_s_setprio(1);
#pragma unroll
  for (int kv = 0; kv < 8; ++kv) {
    FragU pbA, pbB;
    pbA.u[0] = pkuA[4 * kv + 0]; pbA.u[1] = pkuA[4 * kv + 1];
    pbA.u[2] = pkuA[4 * kv + 2]; pbA.u[3] = pkuA[4 * kv + 3];
    pbB.u[0] = pkuB[4 * kv + 0]; pbB.u[1] = pkuB[4 * kv + 1];
    pbB.u[2] = pkuB[4 * kv + 2]; pbB.u[3] = pkuB[4 * kv + 3];
    const char* pv = (kv & 1) ? pm : pp;
    FragU va0, va1;
    va0.q = *(const uint4*)(pv + kv * 64);
    va1.q = *(const uint4*)(pv + kv * 64 + 8192);
    oA0 = __builtin_amdgcn_mfma_f32_16x16x32_bf16(va0.v, pbA.v, oA0, 0, 0, 0);
    oA1 = __builtin_amdgcn_mfma_f32_16x16x32_bf16(va1.v, pbA.v, oA1, 0, 0, 0);
    oB0 = __builtin_amdgcn_mfma_f32_16x16x32_bf16(va0.v, pbB.v, oB0, 0, 0, 0);
    oB1 = __builtin_amdgcn_mfma_f32_16x16x32_bf16(va1.v, pbB.v, oB1, 0, 0, 0);
    saA = __builtin_amdgcn_mfma_f32_16x16x32_bf16(ones.v, pbA.v, saA, 0, 0, 0);
    saB = __builtin_amdgcn_mfma_f32_16x16x32_bf16(ones.v, pbB.v, saB, 0, 0, 0);
  }
  __builtin_amdgcn_s_setprio(0);

  float invA = __builtin_amdgcn_rcpf(saA[0]);  // all 4 rows identical = lsum
  float invB = __builtin_amdgcn_rcpf(saB[0]);
  {
    char* ob = (char*)Ks;  // Olds: 128 rows x 80B
    int nnA = w * 32 + lq, nnB = nnA + 16;
    *(uint2*)(ob + nnA * 80 + g * 8) =
        make_uint2(pk2(oA0[0] * invA, oA0[1] * invA), pk2(oA0[2] * invA, oA0[3] * invA));
    *(uint2*)(ob + nnA * 80 + 32 + g * 8) =
        make_uint2(pk2(oA1[0] * invA, oA1[1] * invA), pk2(oA1[2] * invA, oA1[3] * invA));
    *(uint2*)(ob + nnB * 80 + g * 8) =
        make_uint2(pk2(oB0[0] * invB, oB0[1] * invB), pk2(oB0[2] * invB, oB0[3] * invB));
    *(uint2*)(ob + nnB * 80 + 32 + g * 8) =
        make_uint2(pk2(oB1[0] * invB, oB1[1] * invB), pk2(oB1[2] * invB, oB1[3] * invB));
  }
  __syncthreads();
#pragma unroll
  for (int rep = 0; rep < 2; ++rep) {
    int idx = rep * 256 + t;
    int nn = idx >> 2, dq = idx & 3;
    uint4 v = *(const uint4*)((const char*)Ks + nn * 80 + dq * 16);
    *(uint4*)(ObT + ((size_t)b * 4096 + (xq << 7) + nn) * 512 +
              set * 256 + h * 32 + dq * 8) = v;
  }
}

// ---------------------------------------------------------------------------
// Output projection: 128x128-tile 2-phase LDS-staged MFMA GEMM (R8 config).
// out = wproj(256x512) x ObT^T + bias, fp32.  grid (32 n, 2 m, 8 b), blk 256.
// ---------------------------------------------------------------------------
__global__ __launch_bounds__(256) void k_gemm_proj(
    const u16* __restrict__ XT, const u16* __restrict__ Wb,
    const float* __restrict__ bias, float* __restrict__ Y) {
  __shared__ __align__(16) u16 SM[16384];
  int n0 = blockIdx.x * 128, m0 = blockIdx.y * 128, b = blockIdx.z;
  int t = threadIdx.x, w = t >> 6, l = t & 63, g = l >> 4, lq = l & 15;
  int wr = w >> 1, wc = w & 1;
  const u16* Xb = XT + (size_t)b * 4096 * 512;
  int srow = w * 32 + (l >> 2), scol = (l & 3) * 8;
  const u16* gA = Wb + (size_t)(m0 + srow) * 512 + scol;
  const u16* gB = Xb + (size_t)(n0 + srow) * 512 + scol;
  u16* lA = SM + w * 1024;
  u16* lB = SM + 8192 + w * 1024;

  f32x4 acc[4][4];
#pragma unroll
  for (int ms = 0; ms < 4; ++ms)
#pragma unroll
    for (int ns = 0; ns < 4; ++ns) acc[ms][ns] = {0.f, 0.f, 0.f, 0.f};

  gl16(gA, lA); gl16(gA + 16 * 512, lA + 512);
  gl16(gB, lB); gl16(gB + 16 * 512, lB + 512);
  waitvm0();
  __syncthreads();
#pragma unroll
  for (int kt = 0; kt < 16; ++kt) {
    int cur = kt & 1;
    if (kt < 15) {
      int sel = cur ^ 1, ko = (kt + 1) * 32;
      gl16(gA + ko, lA + sel * 4096); gl16(gA + 16 * 512 + ko, lA + sel * 4096 + 512);
      gl16(gB + ko, lB + sel * 4096); gl16(gB + 16 * 512 + ko, lB + sel * 4096 + 512);
    }
    const u16* Ab = SM + cur * 4096;
    const u16* Bb = SM + 8192 + cur * 4096;
    FragU a[4], bb[4];
#pragma unroll
    for (int ms = 0; ms < 4; ++ms)
      a[ms].q = *(const uint4*)(Ab + (wr * 64 + ms * 16 + lq) * 32 + g * 8);
#pragma unroll
    for (int ns = 0; ns < 4; ++ns)
      bb[ns].q = *(const uint4*)(Bb + (wc * 64 + ns * 16 + lq) * 32 + g * 8);
#pragma unroll
    for (int ms = 0; ms < 4; ++ms)
#pragma unroll
      for (int ns = 0; ns < 4; ++ns)
        acc[ms][ns] = __builtin_amdgcn_mfma_f32_16x16x32_bf16(a[ms].v, bb[ns].v, acc[ms][ns], 0, 0, 0);
    waitvm0();
    __syncthreads();
  }
#pragma unroll
  for (int ms = 0; ms < 4; ++ms)
#pragma unroll
    for (int ns = 0; ns < 4; ++ns) {
      int n = n0 + wc * 64 + ns * 16 + lq;
#pragma unroll
      for (int r = 0; r < 4; ++r) {
        int m = m0 + wr * 64 + ms * 16 + g * 4 + r;
        Y[((size_t)b * 256 + m) * 4096 + n] = acc[ms][ns][r] + bias[m];
      }
    }
}

// ---------------------------------------------------------------------------

extern "C" void kernel_launch(void* const* d_in, const int* in_sizes, int n_in,
                              void* d_out, int out_size, void* d_ws, size_t ws_size,
                              hipStream_t stream) {
  (void)in_sizes; (void)n_in; (void)out_size; (void)ws_size;
  const float* x     = (const float*)d_in[0];
  const float* wq    = (const float*)d_in[1];
  const float* bq    = (const float*)d_in[2];
  const float* wsw   = (const float*)d_in[3];
  const float* bs    = (const float*)d_in[4];
  const float* wak_d = (const float*)d_in[5];
  const float* bak_d = (const float*)d_in[6];
  const float* wak_p = (const float*)d_in[7];
  const float* bak_p = (const float*)d_in[8];
  const float* wav_d = (const float*)d_in[9];
  const float* bav_d = (const float*)d_in[10];
  const float* wav_p = (const float*)d_in[11];
  const float* bav_p = (const float*)d_in[12];
  const float* wek   = (const float*)d_in[13];
  const float* bek   = (const float*)d_in[14];
  const float* wev   = (const float*)d_in[15];
  const float* bev   = (const float*)d_in[16];
  const float* wproj = (const float*)d_in[17];
  const float* bproj = (const float*)d_in[18];
  float* out = (float*)d_out;

  char* p = (char*)d_ws;
  u16* xbT  = (u16*)p;   p += (size_t)8 * 4096 * 256 * 2;     // 16.8 MB
  u16* qb   = (u16*)p;   p += (size_t)8 * 16 * 4096 * 32 * 2; // 33.6 MB
  u16* obT  = (u16*)p;   p += (size_t)8 * 4096 * 512 * 2;     // 33.6 MB
  float* psr = (float*)p; p += (size_t)8 * 8 * 256 * 256 * 4; // 16.8 MB
  u16* xrT  = (u16*)p;   p += (size_t)524288 * 2;
  u16* tkT  = (u16*)p;   p += (size_t)524288 * 2;
  u16* tvT  = (u16*)p;   p += (size_t)524288 * 2;
  u16* kvimg = (u16*)p;  p += (size_t)4 * 64 * 8192 * 2;      // 4.2 MB
  u16* wqb  = (u16*)p;   p += (size_t)131072 * 2;
  u16* wpb  = (u16*)p;   p += (size_t)131072 * 2;
  u16* wsb  = (u16*)p;   p += (size_t)1048576 * 2;
  u16* wkvb = (u16*)p;   p += (size_t)262144 * 2;

  k_xT<<<dim3(64, 8, 9), 256, 0, stream>>>(x, xbT, wq, wproj, wsw,
                                           wak_p, wav_p, wek, wev,
                                           wqb, wpb, wsb, wkvb);
  k_gemm_x<<<dim3(40, 4, 8), 256, 0, stream>>>(xbT, wqb, bq, qb, wsb, psr);
  k_srdw<<<dim3(16, 8), 256, 0, stream>>>(psr, bs, wak_d, bak_d, wav_d, bav_d,
                                          xrT, tkT, tvT);
  k_gemm_kv<<<dim3(4, 8, 8), 256, 0, stream>>>(xrT, tkT, tvT, wkvb,
                                               bak_p, bav_p, bek, bev, kvimg);
  k_attn_mfma<<<dim3(32, 8, 16), 256, 0, stream>>>(qb, kvimg, obT);
  k_gemm_proj<<<dim3(32, 2, 8), 256, 0, stream>>>(obT, wpb, bproj, out);
}